// Round 7
// baseline (335.196 us; speedup 1.0000x reference)
//
#include <hip/hip_runtime.h>

#define N_NODES 100000
#define N_EDGES 1600000
#define IN_DIM 64
#define H_DIM 128
#define OUT_DIM 64
#define BN_EPS 1e-5f
#define CAP 64        // padded-CSR capacity; deg ~ Poisson(16), max ~45 over 100K draws

// ---- workspace layout (float offsets, no aliasing) ----
// [0    .. 3.2M)   : xb (bf16 x, 6.4M ushort)
// [3.2M .. 9.6M)   : srcl (int 6.4M = 100K x CAP)
// [9.6M .. 12.8M)  : comb (bf16, 6.4M ushort)
// [12.8M.. 19.2M)  : h1 (bf16, 12.8M ushort)
// [19.2M.. 22.4M)  : h2 (bf16, 6.4M ushort)
// [22.4M.. 22.5M)  : cnt (int 100K)
// [22.6M..       ) : stats(768)
#define OFF_XB     0
#define OFF_SRCL   3200000
#define OFF_COMB   9600000
#define OFF_H1     12800000
#define OFF_H2     19200000
#define OFF_CNT    22400000
#define OFF_STATS  22600000
#define S1SUM 0
#define S1SQ  128
#define S2SUM 256
#define S2SQ  320

#define DEV_ATOMIC_ADD(p, v) __hip_atomic_fetch_add((p), (v), __ATOMIC_RELAXED, __HIP_MEMORY_SCOPE_AGENT)

typedef __attribute__((ext_vector_type(8))) short short8;
typedef __attribute__((ext_vector_type(4))) float f32x4;

__device__ __forceinline__ unsigned short f2bf(float f) {
  union { float f; unsigned u; } v; v.f = f;
  unsigned r = v.u + 0x7FFFu + ((v.u >> 16) & 1u);
  return (unsigned short)(r >> 16);
}
__device__ __forceinline__ float bflo(unsigned v) { union { unsigned u; float f; } t; t.u = v << 16; return t.f; }
__device__ __forceinline__ float bfhi(unsigned v) { union { unsigned u; float f; } t; t.u = v & 0xFFFF0000u; return t.f; }

__device__ __forceinline__ void acc8(float* a, uint4 v) {
  a[0] += bflo(v.x); a[1] += bfhi(v.x); a[2] += bflo(v.y); a[3] += bfhi(v.y);
  a[4] += bflo(v.z); a[5] += bfhi(v.z); a[6] += bflo(v.w); a[7] += bfhi(v.w);
}
__device__ __forceinline__ uint4 pack8(const float* a) {
  uint4 o;
  o.x = (unsigned)f2bf(a[0]) | ((unsigned)f2bf(a[1]) << 16);
  o.y = (unsigned)f2bf(a[2]) | ((unsigned)f2bf(a[3]) << 16);
  o.z = (unsigned)f2bf(a[4]) | ((unsigned)f2bf(a[5]) << 16);
  o.w = (unsigned)f2bf(a[6]) | ((unsigned)f2bf(a[7]) << 16);
  return o;
}

// ---- build: x fp32->bf16 conversion (stream 1) + direct global-atomic CSR fill
//      (stream 2). Replaces the bsplit+bfill pair: no binned staging round-trip. ----
__global__ __launch_bounds__(256) void k_build(const float* __restrict__ x,
                                               unsigned short* __restrict__ xb,
                                               const int* __restrict__ ei,
                                               int* __restrict__ cnt,
                                               int* __restrict__ srcl) {
  const int tid = threadIdx.x;
  // stream 1: convert 2048 float4 per block
  #pragma unroll
  for (int j = 0; j < 8; ++j) {
    int i = blockIdx.x * 2048 + j * 256 + tid;
    if (i < N_NODES * IN_DIM / 4) {
      float4 v = ((const float4*)x)[i];
      ushort4 o;
      o.x = f2bf(v.x); o.y = f2bf(v.y); o.z = f2bf(v.z); o.w = f2bf(v.w);
      *(ushort4*)(xb + i * 4) = o;
    }
  }
  // stream 2: 2048 edges per block, global ticket + scattered src write
  #pragma unroll
  for (int j = 0; j < 8; ++j) {
    int e = blockIdx.x * 2048 + j * 256 + tid;
    if (e < N_EDGES) {
      int src = ei[e];
      int dst = ei[N_EDGES + e];
      int pos = DEV_ATOMIC_ADD(&cnt[dst], 1);
      if (pos < CAP) srcl[dst * CAP + pos] = src;
    }
  }
}

// ---- gather: comb(bf16) = (1+eps)*x + sum(neighbors), LDS-free deep-MLP streaming ----
__global__ __launch_bounds__(256, 5) void k_gather(const unsigned short* __restrict__ xb,
                                                   const float* __restrict__ eps,
                                                   const int* __restrict__ cnt,
                                                   const int* __restrict__ srcl,
                                                   unsigned short* __restrict__ comb) {
  const int t = blockIdx.x * 256 + threadIdx.x;
  const int node = t >> 3;
  const int sub = t & 7;
  if (node >= N_NODES) return;

  float a[8];
  {
    uint4 sv = *(const uint4*)(xb + node * 64 + sub * 8);
    float e1 = 1.0f + eps[0];
    a[0] = bflo(sv.x) * e1; a[1] = bfhi(sv.x) * e1;
    a[2] = bflo(sv.y) * e1; a[3] = bfhi(sv.y) * e1;
    a[4] = bflo(sv.z) * e1; a[5] = bfhi(sv.z) * e1;
    a[6] = bflo(sv.w) * e1; a[7] = bfhi(sv.w) * e1;
  }
  int deg = cnt[node];
  if (deg > CAP) deg = CAP;
  const int* sl = srcl + node * CAP;

  uint4 n0 = *(const uint4*)sl;
  uint4 n1 = *(const uint4*)(sl + 4);
  int j = 0;
  while (j + 8 <= deg) {
    uint4 i0 = n0, i1 = n1;
    uint4 r0 = *(const uint4*)(xb + (size_t)i0.x * 64 + sub * 8);
    uint4 r1 = *(const uint4*)(xb + (size_t)i0.y * 64 + sub * 8);
    uint4 r2 = *(const uint4*)(xb + (size_t)i0.z * 64 + sub * 8);
    uint4 r3 = *(const uint4*)(xb + (size_t)i0.w * 64 + sub * 8);
    uint4 r4 = *(const uint4*)(xb + (size_t)i1.x * 64 + sub * 8);
    uint4 r5 = *(const uint4*)(xb + (size_t)i1.y * 64 + sub * 8);
    uint4 r6 = *(const uint4*)(xb + (size_t)i1.z * 64 + sub * 8);
    uint4 r7 = *(const uint4*)(xb + (size_t)i1.w * 64 + sub * 8);
    j += 8;
    n0 = *(const uint4*)(sl + j);
    n1 = *(const uint4*)(sl + j + 4);
    acc8(a, r0); acc8(a, r1); acc8(a, r2); acc8(a, r3);
    acc8(a, r4); acc8(a, r5); acc8(a, r6); acc8(a, r7);
  }
  if (j + 4 <= deg) {
    uint4 i0 = *(const uint4*)(sl + j);
    uint4 r0 = *(const uint4*)(xb + (size_t)i0.x * 64 + sub * 8);
    uint4 r1 = *(const uint4*)(xb + (size_t)i0.y * 64 + sub * 8);
    uint4 r2 = *(const uint4*)(xb + (size_t)i0.z * 64 + sub * 8);
    uint4 r3 = *(const uint4*)(xb + (size_t)i0.w * 64 + sub * 8);
    acc8(a, r0); acc8(a, r1); acc8(a, r2); acc8(a, r3);
    j += 4;
  }
  if (j + 2 <= deg) {
    int2 i2 = *(const int2*)(sl + j);
    uint4 r0 = *(const uint4*)(xb + (size_t)i2.x * 64 + sub * 8);
    uint4 r1 = *(const uint4*)(xb + (size_t)i2.y * 64 + sub * 8);
    acc8(a, r0); acc8(a, r1);
    j += 2;
  }
  if (j < deg) {
    int s0 = sl[j];
    uint4 r0 = *(const uint4*)(xb + (size_t)s0 * 64 + sub * 8);
    acc8(a, r0);
  }
  *(uint4*)(comb + node * 64 + sub * 8) = pack8(a);
}

// ---- gemm1: h1(bf16) = comb @ W1 + b1 (bf16 MFMA), fused BN1 raw stats ----
#define APAD 72
__global__ __launch_bounds__(256) void k_gemm1(const unsigned short* __restrict__ comb,
                                               const float* __restrict__ W1,
                                               const float* __restrict__ b1,
                                               unsigned short* __restrict__ h1,
                                               float* __restrict__ stats) {
  __shared__ unsigned short As[128 * APAD];   // 18 KB
  __shared__ unsigned short Ws[128 * APAD];   // 18 KB
  __shared__ float red[4][128];
  const int tid = threadIdx.x;
  const int wv = tid >> 6, lane = tid & 63;
  const int quad = lane >> 4, ln = lane & 15;
  const int rowBase = blockIdx.x * 128;

  // stage Wt[n][k] bf16 from W1 fp32 [64][128]
  #pragma unroll
  for (int it = 0; it < 8; ++it) {
    int idx = it * 256 + tid;
    int k = idx >> 5, n4 = idx & 31;
    float4 wv1 = *(const float4*)(W1 + k * 128 + n4 * 4);
    Ws[(n4 * 4 + 0) * APAD + k] = f2bf(wv1.x);
    Ws[(n4 * 4 + 1) * APAD + k] = f2bf(wv1.y);
    Ws[(n4 * 4 + 2) * APAD + k] = f2bf(wv1.z);
    Ws[(n4 * 4 + 3) * APAD + k] = f2bf(wv1.w);
  }
  // stage As tile from comb (coalesced bf16x8)
  #pragma unroll
  for (int it = 0; it < 4; ++it) {
    int idx = it * 256 + tid;           // 1024 uint4 = 128 rows x 8
    int row = idx >> 3, ch = idx & 7;
    int g = rowBase * 8 + idx;
    uint4 u = (g < N_NODES * 8) ? ((const uint4*)comb)[g] : make_uint4(0, 0, 0, 0);
    *(uint4*)&As[row * APAD + ch * 8] = u;
  }
  __syncthreads();

  f32x4 acc[2][8];
  #pragma unroll
  for (int mt = 0; mt < 2; ++mt) {
    #pragma unroll
    for (int nt = 0; nt < 8; ++nt) acc[mt][nt] = (f32x4)0.0f;
  }
  const int rw = wv * 32;
  #pragma unroll
  for (int kb = 0; kb < 2; ++kb) {
    short8 a0 = *(short8*)&As[(rw + ln) * APAD + kb * 32 + quad * 8];
    short8 a1 = *(short8*)&As[(rw + 16 + ln) * APAD + kb * 32 + quad * 8];
    #pragma unroll
    for (int nt = 0; nt < 8; ++nt) {
      short8 b = *(short8*)&Ws[(nt * 16 + ln) * APAD + kb * 32 + quad * 8];
      acc[0][nt] = __builtin_amdgcn_mfma_f32_16x16x32_bf16(a0, b, acc[0][nt], 0, 0, 0);
      acc[1][nt] = __builtin_amdgcn_mfma_f32_16x16x32_bf16(a1, b, acc[1][nt], 0, 0, 0);
    }
  }

  float bias[8], s[8], q[8];
  #pragma unroll
  for (int nt = 0; nt < 8; ++nt) { bias[nt] = b1[nt * 16 + ln]; s[nt] = 0.f; q[nt] = 0.f; }
  #pragma unroll
  for (int mt = 0; mt < 2; ++mt) {
    #pragma unroll
    for (int i = 0; i < 4; ++i) {
      int gRow = rowBase + rw + mt * 16 + quad * 4 + i;
      if (gRow < N_NODES) {
        #pragma unroll
        for (int nt = 0; nt < 8; ++nt) {
          float v = acc[mt][nt][i] + bias[nt];
          h1[gRow * 128 + nt * 16 + ln] = f2bf(v);
          s[nt] += v; q[nt] += v * v;
        }
      }
    }
  }
  #pragma unroll
  for (int nt = 0; nt < 8; ++nt) {
    s[nt] += __shfl_xor(s[nt], 16); s[nt] += __shfl_xor(s[nt], 32);
    q[nt] += __shfl_xor(q[nt], 16); q[nt] += __shfl_xor(q[nt], 32);
  }
  if (lane < 16) {
    #pragma unroll
    for (int nt = 0; nt < 8; ++nt) red[wv][nt * 16 + ln] = s[nt];
  }
  __syncthreads();
  if (tid < 128) DEV_ATOMIC_ADD(&stats[S1SUM + tid],
                                red[0][tid] + red[1][tid] + red[2][tid] + red[3][tid]);
  __syncthreads();
  if (lane < 16) {
    #pragma unroll
    for (int nt = 0; nt < 8; ++nt) red[wv][nt * 16 + ln] = q[nt];
  }
  __syncthreads();
  if (tid < 128) DEV_ATOMIC_ADD(&stats[S1SQ + tid],
                                red[0][tid] + red[1][tid] + red[2][tid] + red[3][tid]);
}

// ---- gemm2: h2(bf16) = relu(bn1(h1)) @ W2 + b2 (bf16 MFMA), fused BN2 raw stats ----
#define WPAD 136
__global__ __launch_bounds__(256) void k_gemm2(const unsigned short* __restrict__ h1,
                                               const float* __restrict__ W2,
                                               const float* __restrict__ b2,
                                               const float* __restrict__ g1,
                                               const float* __restrict__ be1,
                                               unsigned short* __restrict__ h2,
                                               float* __restrict__ stats) {
  __shared__ unsigned short As[128 * APAD];
  __shared__ unsigned short Ws[64 * WPAD];
  __shared__ float red[4][64];
  __shared__ float scL[128], shL[128];
  const int tid = threadIdx.x;
  const int wv = tid >> 6, lane = tid & 63;
  const int quad = lane >> 4, ln = lane & 15;
  const int rowBase = blockIdx.x * 128;

  if (tid < 128) {
    float mean = stats[S1SUM + tid] * (1.0f / N_NODES);
    float var = stats[S1SQ + tid] * (1.0f / N_NODES) - mean * mean;
    var = fmaxf(var, 0.0f);
    float sc = g1[tid] * rsqrtf(var + BN_EPS);
    scL[tid] = sc;
    shL[tid] = be1[tid] - mean * sc;
  }
  #pragma unroll
  for (int it = 0; it < 8; ++it) {
    int idx = it * 256 + tid;
    int k = idx >> 4, n4 = idx & 15;
    float4 wv2 = *(const float4*)(W2 + k * 64 + n4 * 4);
    Ws[(n4 * 4 + 0) * WPAD + k] = f2bf(wv2.x);
    Ws[(n4 * 4 + 1) * WPAD + k] = f2bf(wv2.y);
    Ws[(n4 * 4 + 2) * WPAD + k] = f2bf(wv2.z);
    Ws[(n4 * 4 + 3) * WPAD + k] = f2bf(wv2.w);
  }

  f32x4 acc[2][4];
  #pragma unroll
  for (int mt = 0; mt < 2; ++mt) {
    #pragma unroll
    for (int nt = 0; nt < 4; ++nt) acc[mt][nt] = (f32x4)0.0f;
  }
  const int rw = wv * 32;

  for (int kc = 0; kc < 2; ++kc) {
    __syncthreads();
    #pragma unroll
    for (int it = 0; it < 4; ++it) {
      int idx = it * 256 + tid;
      int row = idx >> 3, ch = idx & 7;
      int gRow = rowBase + row;
      uint4 u = (gRow < N_NODES) ? *(const uint4*)(h1 + gRow * 128 + kc * 64 + ch * 8)
                                 : make_uint4(0, 0, 0, 0);
      int kb = kc * 64 + ch * 8;
      float f0 = fmaxf(bflo(u.x) * scL[kb + 0] + shL[kb + 0], 0.f);
      float f1 = fmaxf(bfhi(u.x) * scL[kb + 1] + shL[kb + 1], 0.f);
      float f2 = fmaxf(bflo(u.y) * scL[kb + 2] + shL[kb + 2], 0.f);
      float f3 = fmaxf(bfhi(u.y) * scL[kb + 3] + shL[kb + 3], 0.f);
      float f4 = fmaxf(bflo(u.z) * scL[kb + 4] + shL[kb + 4], 0.f);
      float f5 = fmaxf(bfhi(u.z) * scL[kb + 5] + shL[kb + 5], 0.f);
      float f6 = fmaxf(bflo(u.w) * scL[kb + 6] + shL[kb + 6], 0.f);
      float f7 = fmaxf(bfhi(u.w) * scL[kb + 7] + shL[kb + 7], 0.f);
      uint4 o;
      o.x = (unsigned)f2bf(f0) | ((unsigned)f2bf(f1) << 16);
      o.y = (unsigned)f2bf(f2) | ((unsigned)f2bf(f3) << 16);
      o.z = (unsigned)f2bf(f4) | ((unsigned)f2bf(f5) << 16);
      o.w = (unsigned)f2bf(f6) | ((unsigned)f2bf(f7) << 16);
      *(uint4*)&As[row * APAD + ch * 8] = o;
    }
    __syncthreads();
    #pragma unroll
    for (int kb = 0; kb < 2; ++kb) {
      short8 a0 = *(short8*)&As[(rw + ln) * APAD + kb * 32 + quad * 8];
      short8 a1 = *(short8*)&As[(rw + 16 + ln) * APAD + kb * 32 + quad * 8];
      #pragma unroll
      for (int nt = 0; nt < 4; ++nt) {
        short8 b = *(short8*)&Ws[(nt * 16 + ln) * WPAD + kc * 64 + kb * 32 + quad * 8];
        acc[0][nt] = __builtin_amdgcn_mfma_f32_16x16x32_bf16(a0, b, acc[0][nt], 0, 0, 0);
        acc[1][nt] = __builtin_amdgcn_mfma_f32_16x16x32_bf16(a1, b, acc[1][nt], 0, 0, 0);
      }
    }
  }

  float bias[4], s[4], q[4];
  #pragma unroll
  for (int nt = 0; nt < 4; ++nt) { bias[nt] = b2[nt * 16 + ln]; s[nt] = 0.f; q[nt] = 0.f; }
  #pragma unroll
  for (int mt = 0; mt < 2; ++mt) {
    #pragma unroll
    for (int i = 0; i < 4; ++i) {
      int gRow = rowBase + rw + mt * 16 + quad * 4 + i;
      if (gRow < N_NODES) {
        #pragma unroll
        for (int nt = 0; nt < 4; ++nt) {
          float v = acc[mt][nt][i] + bias[nt];
          h2[gRow * 64 + nt * 16 + ln] = f2bf(v);
          s[nt] += v; q[nt] += v * v;
        }
      }
    }
  }
  #pragma unroll
  for (int nt = 0; nt < 4; ++nt) {
    s[nt] += __shfl_xor(s[nt], 16); s[nt] += __shfl_xor(s[nt], 32);
    q[nt] += __shfl_xor(q[nt], 16); q[nt] += __shfl_xor(q[nt], 32);
  }
  if (lane < 16) {
    #pragma unroll
    for (int nt = 0; nt < 4; ++nt) red[wv][nt * 16 + ln] = s[nt];
  }
  __syncthreads();
  if (tid < 64) DEV_ATOMIC_ADD(&stats[S2SUM + tid],
                               red[0][tid] + red[1][tid] + red[2][tid] + red[3][tid]);
  __syncthreads();
  if (lane < 16) {
    #pragma unroll
    for (int nt = 0; nt < 4; ++nt) red[wv][nt * 16 + ln] = q[nt];
  }
  __syncthreads();
  if (tid < 64) DEV_ATOMIC_ADD(&stats[S2SQ + tid],
                               red[0][tid] + red[1][tid] + red[2][tid] + red[3][tid]);
}

// ---- out = bn2(h2 bf16), per-block BN2 finalize ----
__global__ __launch_bounds__(256) void k_out(const unsigned short* __restrict__ h2,
                                             const float* __restrict__ stats,
                                             const float* __restrict__ g2,
                                             const float* __restrict__ be2,
                                             float* __restrict__ out) {
  __shared__ float scL[64], shL[64];
  const int tid = threadIdx.x;
  if (tid < 64) {
    float mean = stats[S2SUM + tid] * (1.0f / N_NODES);
    float var = stats[S2SQ + tid] * (1.0f / N_NODES) - mean * mean;
    var = fmaxf(var, 0.0f);
    float sc = g2[tid] * rsqrtf(var + BN_EPS);
    scL[tid] = sc;
    shL[tid] = be2[tid] - mean * sc;
  }
  __syncthreads();
  int i = blockIdx.x * 256 + tid;
  if (i < N_NODES * OUT_DIM / 4) {
    int c = i & 15;
    uint2 u = *(const uint2*)(h2 + i * 4);
    float4 v = {bflo(u.x), bfhi(u.x), bflo(u.y), bfhi(u.y)};
    float4 sc = ((const float4*)scL)[c];
    float4 sh = ((const float4*)shL)[c];
    v.x = v.x * sc.x + sh.x;
    v.y = v.y * sc.y + sh.y;
    v.z = v.z * sc.z + sh.z;
    v.w = v.w * sc.w + sh.w;
    ((float4*)out)[i] = v;
  }
}

extern "C" void kernel_launch(void* const* d_in, const int* in_sizes, int n_in,
                              void* d_out, int out_size, void* d_ws, size_t ws_size,
                              hipStream_t stream) {
  const float* x   = (const float*)d_in[0];
  const int*   ei  = (const int*)d_in[1];
  const float* eps = (const float*)d_in[2];
  const float* W1  = (const float*)d_in[3];
  const float* b1  = (const float*)d_in[4];
  const float* g1  = (const float*)d_in[5];
  const float* be1 = (const float*)d_in[6];
  const float* W2  = (const float*)d_in[7];
  const float* b2  = (const float*)d_in[8];
  const float* g2  = (const float*)d_in[9];
  const float* be2 = (const float*)d_in[10];

  float* ws = (float*)d_ws;
  unsigned short* xb     = (unsigned short*)(ws + OFF_XB);
  int*            srcl   = (int*)(ws + OFF_SRCL);
  unsigned short* comb   = (unsigned short*)(ws + OFF_COMB);
  unsigned short* h1     = (unsigned short*)(ws + OFF_H1);
  unsigned short* h2     = (unsigned short*)(ws + OFF_H2);
  int*            cnt    = (int*)(ws + OFF_CNT);
  float*          stats  = ws + OFF_STATS;
  float*          out    = (float*)d_out;

  // zero stats(768) and cnt(100K ints)
  hipMemsetAsync(stats, 0, 768 * sizeof(float), stream);
  hipMemsetAsync(cnt, 0, N_NODES * sizeof(int), stream);

  const int edgeGrid = (N_EDGES + 2047) / 2048;            // 782
  const int gemmGrid = (N_NODES + 127) / 128;              // 782
  const int gatherGrid = (N_NODES * 8 + 255) / 256;        // 3125
  k_build<<<edgeGrid, 256, 0, stream>>>(x, xb, ei, cnt, srcl);
  k_gather<<<gatherGrid, 256, 0, stream>>>(xb, eps, cnt, srcl, comb);
  k_gemm1<<<gemmGrid, 256, 0, stream>>>(comb, W1, b1, h1, stats);
  k_gemm2<<<gemmGrid, 256, 0, stream>>>(h1, W2, b2, g1, be1, h2, stats);
  k_out<<<(N_NODES * OUT_DIM / 4 + 255) / 256, 256, 0, stream>>>(h2, stats, g2, be2, out);
}

// Round 10
// 237.494 us; speedup vs baseline: 1.4114x; 1.4114x over previous
//
#include <hip/hip_runtime.h>

#define N_NODES 100000
#define N_EDGES 1600000
#define IN_DIM 64
#define H_DIM 128
#define OUT_DIM 64
#define BN_EPS 1e-5f
#define CAP 64        // padded-CSR capacity; deg ~ Poisson(16), max ~45 over 100K draws
#define BIN_SHIFT 9
#define BIN_NODES 512
#define NB 256
#define BINCAP 10240  // per-bin edge capacity: mean 8192, sigma~90 -> +22.6 sigma
#define NBIN_BLOCKS ((N_NODES + BIN_NODES - 1) / BIN_NODES)  // 196

// ---- workspace layout (float offsets, no aliasing) ----
// [0    .. 3.2M)   : xb (bf16 x, 6.4M ushort)
// [3.2M .. 9.6M)   : srcl (int 6.4M = 100K x CAP)
// [9.6M .. 12.3M)  : binned (packed int, 256 bins x BINCAP)
// [15.0M.. 18.2M)  : comb (bf16, 6.4M ushort)
// [18.2M.. 24.6M)  : h1 (bf16, 12.8M ushort)
// [24.6M.. 27.8M)  : h2 (bf16, 6.4M ushort)
// [27.8M.. 27.9M)  : cnt (int 100K)
// [28.0M..       ) : stats(768) + bcnt(256)
#define OFF_XB     0
#define OFF_SRCL   3200000
#define OFF_BINNED 9600000
#define OFF_COMB   15000000
#define OFF_H1     18200000
#define OFF_H2     24600000
#define OFF_CNT    27800000
#define OFF_STATS  28000000
#define S1SUM 0
#define S1SQ  128
#define S2SUM 256
#define S2SQ  320

#define DEV_ATOMIC_ADD(p, v) __hip_atomic_fetch_add((p), (v), __ATOMIC_RELAXED, __HIP_MEMORY_SCOPE_AGENT)

typedef __attribute__((ext_vector_type(8))) short short8;
typedef __attribute__((ext_vector_type(4))) float f32x4;

__device__ __forceinline__ unsigned short f2bf(float f) {
  union { float f; unsigned u; } v; v.f = f;
  unsigned r = v.u + 0x7FFFu + ((v.u >> 16) & 1u);
  return (unsigned short)(r >> 16);
}
__device__ __forceinline__ float bflo(unsigned v) { union { unsigned u; float f; } t; t.u = v << 16; return t.f; }
__device__ __forceinline__ float bfhi(unsigned v) { union { unsigned u; float f; } t; t.u = v & 0xFFFF0000u; return t.f; }

__device__ __forceinline__ void acc8(float* a, uint4 v) {
  a[0] += bflo(v.x); a[1] += bfhi(v.x); a[2] += bflo(v.y); a[3] += bfhi(v.y);
  a[4] += bflo(v.z); a[5] += bfhi(v.z); a[6] += bflo(v.w); a[7] += bfhi(v.w);
}
__device__ __forceinline__ uint4 pack8(const float* a) {
  uint4 o;
  o.x = (unsigned)f2bf(a[0]) | ((unsigned)f2bf(a[1]) << 16);
  o.y = (unsigned)f2bf(a[2]) | ((unsigned)f2bf(a[3]) << 16);
  o.z = (unsigned)f2bf(a[4]) | ((unsigned)f2bf(a[5]) << 16);
  o.w = (unsigned)f2bf(a[6]) | ((unsigned)f2bf(a[7]) << 16);
  return o;
}

// ---- bsplit: x fp32->bf16 conversion (stream 1) + single-pass edge multisplit
//      into capacity-padded bins (stream 2). Entries packed: (src<<9)|(dst&511). ----
__global__ __launch_bounds__(256) void k_bsplit(const float* __restrict__ x,
                                                unsigned short* __restrict__ xb,
                                                const int* __restrict__ ei,
                                                int* __restrict__ bcnt,
                                                int* __restrict__ binned) {
  __shared__ int lcnt[NB];
  __shared__ int lbase[NB];
  const int tid = threadIdx.x;
  lcnt[tid] = 0;
  // stream 1: convert 2048 float4 per block
  #pragma unroll
  for (int j = 0; j < 8; ++j) {
    int i = blockIdx.x * 2048 + j * 256 + tid;
    if (i < N_NODES * IN_DIM / 4) {
      float4 v = ((const float4*)x)[i];
      ushort4 o;
      o.x = f2bf(v.x); o.y = f2bf(v.y); o.z = f2bf(v.z); o.w = f2bf(v.w);
      *(ushort4*)(xb + i * 4) = o;
    }
  }
  __syncthreads();
  // stream 2: 2048 edges per block, LDS rank + global bin reservation
  int src[8], dst[8], rk[8];
  #pragma unroll
  for (int j = 0; j < 8; ++j) {
    int e = blockIdx.x * 2048 + j * 256 + tid;
    if (e < N_EDGES) {
      src[j] = ei[e];
      dst[j] = ei[N_EDGES + e];
      rk[j] = atomicAdd(&lcnt[dst[j] >> BIN_SHIFT], 1);
    } else {
      src[j] = -1;
    }
  }
  __syncthreads();
  if (lcnt[tid] > 0) lbase[tid] = DEV_ATOMIC_ADD(&bcnt[tid], lcnt[tid]);
  __syncthreads();
  #pragma unroll
  for (int j = 0; j < 8; ++j) {
    if (src[j] >= 0) {
      int b = dst[j] >> BIN_SHIFT;
      int pos = lbase[b] + rk[j];
      if (pos < BINCAP)
        binned[b * BINCAP + pos] = (src[j] << BIN_SHIFT) | (dst[j] & (BIN_NODES - 1));
    }
  }
}

// ---- per-bin CSR fill (XCD-local scatter, LDS tickets), packed entries ----
__global__ __launch_bounds__(512) void k_bfill(const int* __restrict__ bcnt,
                                               const int* __restrict__ binned,
                                               int* __restrict__ cnt,
                                               int* __restrict__ srcl) {
  __shared__ int lcnt[BIN_NODES];
  const int tid = threadIdx.x;
  for (int i = tid; i < BIN_NODES; i += 512) lcnt[i] = 0;
  __syncthreads();
  const int b = blockIdx.x;
  int n = bcnt[b];
  if (n > BINCAP) n = BINCAP;
  const int* run = binned + b * BINCAP;
  const int base = b * BIN_NODES;
  for (int i = tid; i < n; i += 512) {
    int p = run[i];
    int lid = p & (BIN_NODES - 1);
    int pos = atomicAdd(&lcnt[lid], 1);
    if (pos < CAP) srcl[(base + lid) * CAP + pos] = p >> BIN_SHIFT;
  }
  __syncthreads();
  for (int i = tid; i < BIN_NODES; i += 512) {
    int node = base + i;
    if (node < N_NODES) cnt[node] = lcnt[i];
  }
}

// ---- gather: comb(bf16) = (1+eps)*x + sum(neighbors) ----
// 16 lanes/node: two 8-lane groups own alternating 4-edge blocks of the
// neighbor list (4-aligned uint4 index loads), partial sums combined via
// shfl_xor(8). Halves the serial chain vs 8-lane version.
__global__ __launch_bounds__(256, 6) void k_gather(const unsigned short* __restrict__ xb,
                                                   const float* __restrict__ eps,
                                                   const int* __restrict__ cnt,
                                                   const int* __restrict__ srcl,
                                                   unsigned short* __restrict__ comb) {
  const int t = blockIdx.x * 256 + threadIdx.x;
  const int node = t >> 4;
  const int g = (t >> 3) & 1;
  const int sub = t & 7;
  if (node >= N_NODES) return;

  const unsigned short* xs = xb + sub * 8;
  float a[8];
  #pragma unroll
  for (int i = 0; i < 8; ++i) a[i] = 0.f;

  if (g == 0) {
    uint4 sv = *(const uint4*)(xb + node * 64 + sub * 8);
    float e1 = 1.0f + eps[0];
    a[0] = bflo(sv.x) * e1; a[1] = bfhi(sv.x) * e1;
    a[2] = bflo(sv.y) * e1; a[3] = bfhi(sv.y) * e1;
    a[4] = bflo(sv.z) * e1; a[5] = bfhi(sv.z) * e1;
    a[6] = bflo(sv.w) * e1; a[7] = bfhi(sv.w) * e1;
  }
  int deg = cnt[node];
  if (deg > CAP) deg = CAP;
  const int* sl = srcl + node * CAP;

  int j = g * 4;
  // two owned 4-edge blocks per iteration: 8 row loads in flight
  while (j + 12 <= deg) {
    uint4 i0 = *(const uint4*)(sl + j);
    uint4 i1 = *(const uint4*)(sl + j + 8);
    uint4 r0 = *(const uint4*)(xs + (size_t)i0.x * 64);
    uint4 r1 = *(const uint4*)(xs + (size_t)i0.y * 64);
    uint4 r2 = *(const uint4*)(xs + (size_t)i0.z * 64);
    uint4 r3 = *(const uint4*)(xs + (size_t)i0.w * 64);
    uint4 r4 = *(const uint4*)(xs + (size_t)i1.x * 64);
    uint4 r5 = *(const uint4*)(xs + (size_t)i1.y * 64);
    uint4 r6 = *(const uint4*)(xs + (size_t)i1.z * 64);
    uint4 r7 = *(const uint4*)(xs + (size_t)i1.w * 64);
    acc8(a, r0); acc8(a, r1); acc8(a, r2); acc8(a, r3);
    acc8(a, r4); acc8(a, r5); acc8(a, r6); acc8(a, r7);
    j += 16;
  }
  // at most one full owned block remains
  if (j + 4 <= deg) {
    uint4 i0 = *(const uint4*)(sl + j);
    uint4 r0 = *(const uint4*)(xs + (size_t)i0.x * 64);
    uint4 r1 = *(const uint4*)(xs + (size_t)i0.y * 64);
    uint4 r2 = *(const uint4*)(xs + (size_t)i0.z * 64);
    uint4 r3 = *(const uint4*)(xs + (size_t)i0.w * 64);
    acc8(a, r0); acc8(a, r1); acc8(a, r2); acc8(a, r3);
  }
  // tail block (deg % 4 edges) handled by its owner group
  if (g == ((deg >> 2) & 1)) {
    for (int k = deg & ~3; k < deg; ++k) {
      int s0 = sl[k];
      uint4 r = *(const uint4*)(xs + (size_t)s0 * 64);
      acc8(a, r);
    }
  }
  // combine the two groups' partial sums
  #pragma unroll
  for (int i = 0; i < 8; ++i) a[i] += __shfl_xor(a[i], 8);
  if (g == 0) *(uint4*)(comb + node * 64 + sub * 8) = pack8(a);
}

// ---- gemm1: h1(bf16) = comb @ W1 + b1 (bf16 MFMA), fused BN1 raw stats ----
#define APAD 72
__global__ __launch_bounds__(256) void k_gemm1(const unsigned short* __restrict__ comb,
                                               const float* __restrict__ W1,
                                               const float* __restrict__ b1,
                                               unsigned short* __restrict__ h1,
                                               float* __restrict__ stats) {
  __shared__ unsigned short As[128 * APAD];   // 18 KB
  __shared__ unsigned short Ws[128 * APAD];   // 18 KB
  __shared__ float red[4][128];
  const int tid = threadIdx.x;
  const int wv = tid >> 6, lane = tid & 63;
  const int quad = lane >> 4, ln = lane & 15;
  const int rowBase = blockIdx.x * 128;

  // stage Wt[n][k] bf16 from W1 fp32 [64][128]
  #pragma unroll
  for (int it = 0; it < 8; ++it) {
    int idx = it * 256 + tid;
    int k = idx >> 5, n4 = idx & 31;
    float4 wv1 = *(const float4*)(W1 + k * 128 + n4 * 4);
    Ws[(n4 * 4 + 0) * APAD + k] = f2bf(wv1.x);
    Ws[(n4 * 4 + 1) * APAD + k] = f2bf(wv1.y);
    Ws[(n4 * 4 + 2) * APAD + k] = f2bf(wv1.z);
    Ws[(n4 * 4 + 3) * APAD + k] = f2bf(wv1.w);
  }
  // stage As tile from comb (coalesced bf16x8)
  #pragma unroll
  for (int it = 0; it < 4; ++it) {
    int idx = it * 256 + tid;           // 1024 uint4 = 128 rows x 8
    int row = idx >> 3, ch = idx & 7;
    int g = rowBase * 8 + idx;
    uint4 u = (g < N_NODES * 8) ? ((const uint4*)comb)[g] : make_uint4(0, 0, 0, 0);
    *(uint4*)&As[row * APAD + ch * 8] = u;
  }
  __syncthreads();

  f32x4 acc[2][8];
  #pragma unroll
  for (int mt = 0; mt < 2; ++mt) {
    #pragma unroll
    for (int nt = 0; nt < 8; ++nt) acc[mt][nt] = (f32x4)0.0f;
  }
  const int rw = wv * 32;
  #pragma unroll
  for (int kb = 0; kb < 2; ++kb) {
    short8 a0 = *(short8*)&As[(rw + ln) * APAD + kb * 32 + quad * 8];
    short8 a1 = *(short8*)&As[(rw + 16 + ln) * APAD + kb * 32 + quad * 8];
    #pragma unroll
    for (int nt = 0; nt < 8; ++nt) {
      short8 b = *(short8*)&Ws[(nt * 16 + ln) * APAD + kb * 32 + quad * 8];
      acc[0][nt] = __builtin_amdgcn_mfma_f32_16x16x32_bf16(a0, b, acc[0][nt], 0, 0, 0);
      acc[1][nt] = __builtin_amdgcn_mfma_f32_16x16x32_bf16(a1, b, acc[1][nt], 0, 0, 0);
    }
  }

  float bias[8], s[8], q[8];
  #pragma unroll
  for (int nt = 0; nt < 8; ++nt) { bias[nt] = b1[nt * 16 + ln]; s[nt] = 0.f; q[nt] = 0.f; }
  #pragma unroll
  for (int mt = 0; mt < 2; ++mt) {
    #pragma unroll
    for (int i = 0; i < 4; ++i) {
      int gRow = rowBase + rw + mt * 16 + quad * 4 + i;
      if (gRow < N_NODES) {
        #pragma unroll
        for (int nt = 0; nt < 8; ++nt) {
          float v = acc[mt][nt][i] + bias[nt];
          h1[gRow * 128 + nt * 16 + ln] = f2bf(v);
          s[nt] += v; q[nt] += v * v;
        }
      }
    }
  }
  #pragma unroll
  for (int nt = 0; nt < 8; ++nt) {
    s[nt] += __shfl_xor(s[nt], 16); s[nt] += __shfl_xor(s[nt], 32);
    q[nt] += __shfl_xor(q[nt], 16); q[nt] += __shfl_xor(q[nt], 32);
  }
  if (lane < 16) {
    #pragma unroll
    for (int nt = 0; nt < 8; ++nt) red[wv][nt * 16 + ln] = s[nt];
  }
  __syncthreads();
  if (tid < 128) DEV_ATOMIC_ADD(&stats[S1SUM + tid],
                                red[0][tid] + red[1][tid] + red[2][tid] + red[3][tid]);
  __syncthreads();
  if (lane < 16) {
    #pragma unroll
    for (int nt = 0; nt < 8; ++nt) red[wv][nt * 16 + ln] = q[nt];
  }
  __syncthreads();
  if (tid < 128) DEV_ATOMIC_ADD(&stats[S1SQ + tid],
                                red[0][tid] + red[1][tid] + red[2][tid] + red[3][tid]);
}

// ---- gemm2: h2(bf16) = relu(bn1(h1)) @ W2 + b2 (bf16 MFMA), fused BN2 raw stats ----
#define WPAD 136
__global__ __launch_bounds__(256) void k_gemm2(const unsigned short* __restrict__ h1,
                                               const float* __restrict__ W2,
                                               const float* __restrict__ b2,
                                               const float* __restrict__ g1,
                                               const float* __restrict__ be1,
                                               unsigned short* __restrict__ h2,
                                               float* __restrict__ stats) {
  __shared__ unsigned short As[128 * APAD];
  __shared__ unsigned short Ws[64 * WPAD];
  __shared__ float red[4][64];
  __shared__ float scL[128], shL[128];
  const int tid = threadIdx.x;
  const int wv = tid >> 6, lane = tid & 63;
  const int quad = lane >> 4, ln = lane & 15;
  const int rowBase = blockIdx.x * 128;

  if (tid < 128) {
    float mean = stats[S1SUM + tid] * (1.0f / N_NODES);
    float var = stats[S1SQ + tid] * (1.0f / N_NODES) - mean * mean;
    var = fmaxf(var, 0.0f);
    float sc = g1[tid] * rsqrtf(var + BN_EPS);
    scL[tid] = sc;
    shL[tid] = be1[tid] - mean * sc;
  }
  #pragma unroll
  for (int it = 0; it < 8; ++it) {
    int idx = it * 256 + tid;
    int k = idx >> 4, n4 = idx & 15;
    float4 wv2 = *(const float4*)(W2 + k * 64 + n4 * 4);
    Ws[(n4 * 4 + 0) * WPAD + k] = f2bf(wv2.x);
    Ws[(n4 * 4 + 1) * WPAD + k] = f2bf(wv2.y);
    Ws[(n4 * 4 + 2) * WPAD + k] = f2bf(wv2.z);
    Ws[(n4 * 4 + 3) * WPAD + k] = f2bf(wv2.w);
  }

  f32x4 acc[2][4];
  #pragma unroll
  for (int mt = 0; mt < 2; ++mt) {
    #pragma unroll
    for (int nt = 0; nt < 4; ++nt) acc[mt][nt] = (f32x4)0.0f;
  }
  const int rw = wv * 32;

  for (int kc = 0; kc < 2; ++kc) {
    __syncthreads();
    #pragma unroll
    for (int it = 0; it < 4; ++it) {
      int idx = it * 256 + tid;
      int row = idx >> 3, ch = idx & 7;
      int gRow = rowBase + row;
      uint4 u = (gRow < N_NODES) ? *(const uint4*)(h1 + gRow * 128 + kc * 64 + ch * 8)
                                 : make_uint4(0, 0, 0, 0);
      int kb = kc * 64 + ch * 8;
      float f0 = fmaxf(bflo(u.x) * scL[kb + 0] + shL[kb + 0], 0.f);
      float f1 = fmaxf(bfhi(u.x) * scL[kb + 1] + shL[kb + 1], 0.f);
      float f2 = fmaxf(bflo(u.y) * scL[kb + 2] + shL[kb + 2], 0.f);
      float f3 = fmaxf(bfhi(u.y) * scL[kb + 3] + shL[kb + 3], 0.f);
      float f4 = fmaxf(bflo(u.z) * scL[kb + 4] + shL[kb + 4], 0.f);
      float f5 = fmaxf(bfhi(u.z) * scL[kb + 5] + shL[kb + 5], 0.f);
      float f6 = fmaxf(bflo(u.w) * scL[kb + 6] + shL[kb + 6], 0.f);
      float f7 = fmaxf(bfhi(u.w) * scL[kb + 7] + shL[kb + 7], 0.f);
      uint4 o;
      o.x = (unsigned)f2bf(f0) | ((unsigned)f2bf(f1) << 16);
      o.y = (unsigned)f2bf(f2) | ((unsigned)f2bf(f3) << 16);
      o.z = (unsigned)f2bf(f4) | ((unsigned)f2bf(f5) << 16);
      o.w = (unsigned)f2bf(f6) | ((unsigned)f2bf(f7) << 16);
      *(uint4*)&As[row * APAD + ch * 8] = o;
    }
    __syncthreads();
    #pragma unroll
    for (int kb = 0; kb < 2; ++kb) {
      short8 a0 = *(short8*)&As[(rw + ln) * APAD + kb * 32 + quad * 8];
      short8 a1 = *(short8*)&As[(rw + 16 + ln) * APAD + kb * 32 + quad * 8];
      #pragma unroll
      for (int nt = 0; nt < 4; ++nt) {
        short8 b = *(short8*)&Ws[(nt * 16 + ln) * WPAD + kc * 64 + kb * 32 + quad * 8];
        acc[0][nt] = __builtin_amdgcn_mfma_f32_16x16x32_bf16(a0, b, acc[0][nt], 0, 0, 0);
        acc[1][nt] = __builtin_amdgcn_mfma_f32_16x16x32_bf16(a1, b, acc[1][nt], 0, 0, 0);
      }
    }
  }

  float bias[4], s[4], q[4];
  #pragma unroll
  for (int nt = 0; nt < 4; ++nt) { bias[nt] = b2[nt * 16 + ln]; s[nt] = 0.f; q[nt] = 0.f; }
  #pragma unroll
  for (int mt = 0; mt < 2; ++mt) {
    #pragma unroll
    for (int i = 0; i < 4; ++i) {
      int gRow = rowBase + rw + mt * 16 + quad * 4 + i;
      if (gRow < N_NODES) {
        #pragma unroll
        for (int nt = 0; nt < 4; ++nt) {
          float v = acc[mt][nt][i] + bias[nt];
          h2[gRow * 64 + nt * 16 + ln] = f2bf(v);
          s[nt] += v; q[nt] += v * v;
        }
      }
    }
  }
  #pragma unroll
  for (int nt = 0; nt < 4; ++nt) {
    s[nt] += __shfl_xor(s[nt], 16); s[nt] += __shfl_xor(s[nt], 32);
    q[nt] += __shfl_xor(q[nt], 16); q[nt] += __shfl_xor(q[nt], 32);
  }
  if (lane < 16) {
    #pragma unroll
    for (int nt = 0; nt < 4; ++nt) red[wv][nt * 16 + ln] = s[nt];
  }
  __syncthreads();
  if (tid < 64) DEV_ATOMIC_ADD(&stats[S2SUM + tid],
                               red[0][tid] + red[1][tid] + red[2][tid] + red[3][tid]);
  __syncthreads();
  if (lane < 16) {
    #pragma unroll
    for (int nt = 0; nt < 4; ++nt) red[wv][nt * 16 + ln] = q[nt];
  }
  __syncthreads();
  if (tid < 64) DEV_ATOMIC_ADD(&stats[S2SQ + tid],
                               red[0][tid] + red[1][tid] + red[2][tid] + red[3][tid]);
}

// ---- out = bn2(h2 bf16), per-block BN2 finalize ----
__global__ __launch_bounds__(256) void k_out(const unsigned short* __restrict__ h2,
                                             const float* __restrict__ stats,
                                             const float* __restrict__ g2,
                                             const float* __restrict__ be2,
                                             float* __restrict__ out) {
  __shared__ float scL[64], shL[64];
  const int tid = threadIdx.x;
  if (tid < 64) {
    float mean = stats[S2SUM + tid] * (1.0f / N_NODES);
    float var = stats[S2SQ + tid] * (1.0f / N_NODES) - mean * mean;
    var = fmaxf(var, 0.0f);
    float sc = g2[tid] * rsqrtf(var + BN_EPS);
    scL[tid] = sc;
    shL[tid] = be2[tid] - mean * sc;
  }
  __syncthreads();
  int i = blockIdx.x * 256 + tid;
  if (i < N_NODES * OUT_DIM / 4) {
    int c = i & 15;
    uint2 u = *(const uint2*)(h2 + i * 4);
    float4 v = {bflo(u.x), bfhi(u.x), bflo(u.y), bfhi(u.y)};
    float4 sc = ((const float4*)scL)[c];
    float4 sh = ((const float4*)shL)[c];
    v.x = v.x * sc.x + sh.x;
    v.y = v.y * sc.y + sh.y;
    v.z = v.z * sc.z + sh.z;
    v.w = v.w * sc.w + sh.w;
    ((float4*)out)[i] = v;
  }
}

extern "C" void kernel_launch(void* const* d_in, const int* in_sizes, int n_in,
                              void* d_out, int out_size, void* d_ws, size_t ws_size,
                              hipStream_t stream) {
  const float* x   = (const float*)d_in[0];
  const int*   ei  = (const int*)d_in[1];
  const float* eps = (const float*)d_in[2];
  const float* W1  = (const float*)d_in[3];
  const float* b1  = (const float*)d_in[4];
  const float* g1  = (const float*)d_in[5];
  const float* be1 = (const float*)d_in[6];
  const float* W2  = (const float*)d_in[7];
  const float* b2  = (const float*)d_in[8];
  const float* g2  = (const float*)d_in[9];
  const float* be2 = (const float*)d_in[10];

  float* ws = (float*)d_ws;
  unsigned short* xb     = (unsigned short*)(ws + OFF_XB);
  int*            srcl   = (int*)(ws + OFF_SRCL);
  int*            binned = (int*)(ws + OFF_BINNED);
  unsigned short* comb   = (unsigned short*)(ws + OFF_COMB);
  unsigned short* h1     = (unsigned short*)(ws + OFF_H1);
  unsigned short* h2     = (unsigned short*)(ws + OFF_H2);
  int*            cnt    = (int*)(ws + OFF_CNT);
  float*          stats  = ws + OFF_STATS;
  int*            bcnt   = (int*)(stats + 768);   // 256 ints
  float*          out    = (float*)d_out;

  // memset covers stats(768) + bcnt(256)
  hipMemsetAsync(stats, 0, 1024 * sizeof(float), stream);

  const int edgeGrid = (N_EDGES + 2047) / 2048;            // 782
  const int gemmGrid = (N_NODES + 127) / 128;              // 782
  const int gatherGrid = (N_NODES * 16 + 255) / 256;       // 6250
  k_bsplit<<<edgeGrid, 256, 0, stream>>>(x, xb, ei, bcnt, binned);
  k_bfill<<<NBIN_BLOCKS, 512, 0, stream>>>(bcnt, binned, cnt, srcl);
  k_gather<<<gatherGrid, 256, 0, stream>>>(xb, eps, cnt, srcl, comb);
  k_gemm1<<<gemmGrid, 256, 0, stream>>>(comb, W1, b1, h1, stats);
  k_gemm2<<<gemmGrid, 256, 0, stream>>>(h1, W2, b2, g1, be1, h2, stats);
  k_out<<<(N_NODES * OUT_DIM / 4 + 255) / 256, 256, 0, stream>>>(h2, stats, g2, be2, out);
}

// Round 11
// 230.466 us; speedup vs baseline: 1.4544x; 1.0305x over previous
//
#include <hip/hip_runtime.h>

#define N_NODES 100000
#define N_EDGES 1600000
#define IN_DIM 64
#define H_DIM 128
#define OUT_DIM 64
#define BN_EPS 1e-5f
#define CAP 64        // padded per-node capacity; deg ~ Poisson(16), max ~45 over 100K draws
#define BIN_SHIFT 7
#define BIN_NODES 128
#define NBINS 782     // ceil(100000/128)
#define BINCAP 3072   // per-bin edge capacity: mean 2046, sigma~45 -> +22.8 sigma
// ---- workspace layout (float offsets, no aliasing) ----
// [0    .. 3.2M)   : xb (bf16 x, 6.4M ushort)
// [9.6M .. 12.1M)  : binned (packed int, 782 bins x 3072)
// [15.0M.. 18.2M)  : comb (bf16, 6.4M ushort)
// [18.2M.. 24.6M)  : h1 (bf16, 12.8M ushort)
// [24.6M.. 27.8M)  : h2 (bf16, 6.4M ushort)
// [28.0M..       ) : stats(768) + bcnt(782)
#define OFF_XB     0
#define OFF_BINNED 9600000
#define OFF_COMB   15000000
#define OFF_H1     18200000
#define OFF_H2     24600000
#define OFF_STATS  28000000
#define S1SUM 0
#define S1SQ  128
#define S2SUM 256
#define S2SQ  320

#define DEV_ATOMIC_ADD(p, v) __hip_atomic_fetch_add((p), (v), __ATOMIC_RELAXED, __HIP_MEMORY_SCOPE_AGENT)

typedef __attribute__((ext_vector_type(8))) short short8;
typedef __attribute__((ext_vector_type(4))) float f32x4;

__device__ __forceinline__ unsigned short f2bf(float f) {
  union { float f; unsigned u; } v; v.f = f;
  unsigned r = v.u + 0x7FFFu + ((v.u >> 16) & 1u);
  return (unsigned short)(r >> 16);
}
__device__ __forceinline__ float bflo(unsigned v) { union { unsigned u; float f; } t; t.u = v << 16; return t.f; }
__device__ __forceinline__ float bfhi(unsigned v) { union { unsigned u; float f; } t; t.u = v & 0xFFFF0000u; return t.f; }

__device__ __forceinline__ void acc8(float* a, uint4 v) {
  a[0] += bflo(v.x); a[1] += bfhi(v.x); a[2] += bflo(v.y); a[3] += bfhi(v.y);
  a[4] += bflo(v.z); a[5] += bfhi(v.z); a[6] += bflo(v.w); a[7] += bfhi(v.w);
}
__device__ __forceinline__ uint4 pack8(const float* a) {
  uint4 o;
  o.x = (unsigned)f2bf(a[0]) | ((unsigned)f2bf(a[1]) << 16);
  o.y = (unsigned)f2bf(a[2]) | ((unsigned)f2bf(a[3]) << 16);
  o.z = (unsigned)f2bf(a[4]) | ((unsigned)f2bf(a[5]) << 16);
  o.w = (unsigned)f2bf(a[6]) | ((unsigned)f2bf(a[7]) << 16);
  return o;
}

// ---- bsplit: x fp32->bf16 conversion (stream 1) + single-pass edge multisplit
//      into capacity-padded 128-node bins. Entries packed: (src<<7)|(dst&127). ----
__global__ __launch_bounds__(256) void k_bsplit(const float* __restrict__ x,
                                                unsigned short* __restrict__ xb,
                                                const int* __restrict__ ei,
                                                int* __restrict__ bcnt,
                                                int* __restrict__ binned) {
  __shared__ int lcnt[NBINS];
  __shared__ int lbase[NBINS];
  const int tid = threadIdx.x;
  for (int i = tid; i < NBINS; i += 256) lcnt[i] = 0;
  // stream 1: convert 2048 float4 per block
  #pragma unroll
  for (int j = 0; j < 8; ++j) {
    int i = blockIdx.x * 2048 + j * 256 + tid;
    if (i < N_NODES * IN_DIM / 4) {
      float4 v = ((const float4*)x)[i];
      ushort4 o;
      o.x = f2bf(v.x); o.y = f2bf(v.y); o.z = f2bf(v.z); o.w = f2bf(v.w);
      *(ushort4*)(xb + i * 4) = o;
    }
  }
  __syncthreads();
  // stream 2: 2048 edges per block, LDS rank + global bin reservation
  int src[8], dst[8], rk[8];
  #pragma unroll
  for (int j = 0; j < 8; ++j) {
    int e = blockIdx.x * 2048 + j * 256 + tid;
    if (e < N_EDGES) {
      src[j] = ei[e];
      dst[j] = ei[N_EDGES + e];
      rk[j] = atomicAdd(&lcnt[dst[j] >> BIN_SHIFT], 1);
    } else {
      src[j] = -1;
    }
  }
  __syncthreads();
  for (int i = tid; i < NBINS; i += 256)
    if (lcnt[i] > 0) lbase[i] = DEV_ATOMIC_ADD(&bcnt[i], lcnt[i]);
  __syncthreads();
  #pragma unroll
  for (int j = 0; j < 8; ++j) {
    if (src[j] >= 0) {
      int b = dst[j] >> BIN_SHIFT;
      int pos = lbase[b] + rk[j];
      if (pos < BINCAP)
        binned[b * BINCAP + pos] = (src[j] << BIN_SHIFT) | (dst[j] & (BIN_NODES - 1));
    }
  }
}

// ---- bingather: per-bin CSR build in LDS + 16-lane gather. Replaces bfill+gather:
//      srcl never touches global memory. Block = 512 thr; LDS 32.5 KB. ----
__global__ __launch_bounds__(512) void k_bingather(const unsigned short* __restrict__ xb,
                                                   const float* __restrict__ eps,
                                                   const int* __restrict__ bcnt,
                                                   const int* __restrict__ binned,
                                                   unsigned short* __restrict__ comb) {
  __shared__ int lcnt[BIN_NODES];
  __shared__ int slds[BIN_NODES * CAP];   // 32 KB
  const int tid = threadIdx.x;
  const int b = blockIdx.x;
  for (int i = tid; i < BIN_NODES; i += 512) lcnt[i] = 0;
  __syncthreads();
  // phase A: LDS tickets + neighbor lists in LDS
  int n = bcnt[b];
  if (n > BINCAP) n = BINCAP;
  const int* run = binned + b * BINCAP;
  for (int i = tid; i < n; i += 512) {
    int p = run[i];
    int lid = p & (BIN_NODES - 1);
    int pos = atomicAdd(&lcnt[lid], 1);
    if (pos < CAP) slds[lid * CAP + pos] = p >> BIN_SHIFT;
  }
  __syncthreads();
  // phase B: 16 lanes/node gather (two 8-lane groups own alternating 4-edge blocks)
  const int g = (tid >> 3) & 1;
  const int sub = tid & 7;
  const unsigned short* xs = xb + sub * 8;
  const float e1 = 1.0f + eps[0];
  for (int grp = 0; grp < 4; ++grp) {
    int nl = grp * 32 + (tid >> 4);
    int node = b * BIN_NODES + nl;
    if (node >= N_NODES) continue;

    float a[8];
    #pragma unroll
    for (int i = 0; i < 8; ++i) a[i] = 0.f;
    if (g == 0) {
      uint4 sv = *(const uint4*)(xb + (size_t)node * 64 + sub * 8);
      a[0] = bflo(sv.x) * e1; a[1] = bfhi(sv.x) * e1;
      a[2] = bflo(sv.y) * e1; a[3] = bfhi(sv.y) * e1;
      a[4] = bflo(sv.z) * e1; a[5] = bfhi(sv.z) * e1;
      a[6] = bflo(sv.w) * e1; a[7] = bfhi(sv.w) * e1;
    }
    int deg = lcnt[nl];
    if (deg > CAP) deg = CAP;
    const int* sl = slds + nl * CAP;

    int j = g * 4;
    while (j + 12 <= deg) {
      uint4 i0 = *(const uint4*)(sl + j);       // LDS index reads
      uint4 i1 = *(const uint4*)(sl + j + 8);
      uint4 r0 = *(const uint4*)(xs + (size_t)i0.x * 64);
      uint4 r1 = *(const uint4*)(xs + (size_t)i0.y * 64);
      uint4 r2 = *(const uint4*)(xs + (size_t)i0.z * 64);
      uint4 r3 = *(const uint4*)(xs + (size_t)i0.w * 64);
      uint4 r4 = *(const uint4*)(xs + (size_t)i1.x * 64);
      uint4 r5 = *(const uint4*)(xs + (size_t)i1.y * 64);
      uint4 r6 = *(const uint4*)(xs + (size_t)i1.z * 64);
      uint4 r7 = *(const uint4*)(xs + (size_t)i1.w * 64);
      acc8(a, r0); acc8(a, r1); acc8(a, r2); acc8(a, r3);
      acc8(a, r4); acc8(a, r5); acc8(a, r6); acc8(a, r7);
      j += 16;
    }
    if (j + 4 <= deg) {
      uint4 i0 = *(const uint4*)(sl + j);
      uint4 r0 = *(const uint4*)(xs + (size_t)i0.x * 64);
      uint4 r1 = *(const uint4*)(xs + (size_t)i0.y * 64);
      uint4 r2 = *(const uint4*)(xs + (size_t)i0.z * 64);
      uint4 r3 = *(const uint4*)(xs + (size_t)i0.w * 64);
      acc8(a, r0); acc8(a, r1); acc8(a, r2); acc8(a, r3);
    }
    if (g == ((deg >> 2) & 1)) {
      for (int k = deg & ~3; k < deg; ++k) {
        int s0 = sl[k];
        uint4 r = *(const uint4*)(xs + (size_t)s0 * 64);
        acc8(a, r);
      }
    }
    #pragma unroll
    for (int i = 0; i < 8; ++i) a[i] += __shfl_xor(a[i], 8);
    if (g == 0) *(uint4*)(comb + (size_t)node * 64 + sub * 8) = pack8(a);
  }
}

// ---- gemm1: h1(bf16) = comb @ W1 + b1 (bf16 MFMA), fused BN1 raw stats ----
#define APAD 72
__global__ __launch_bounds__(256) void k_gemm1(const unsigned short* __restrict__ comb,
                                               const float* __restrict__ W1,
                                               const float* __restrict__ b1,
                                               unsigned short* __restrict__ h1,
                                               float* __restrict__ stats) {
  __shared__ unsigned short As[128 * APAD];   // 18 KB
  __shared__ unsigned short Ws[128 * APAD];   // 18 KB
  __shared__ float red[4][128];
  const int tid = threadIdx.x;
  const int wv = tid >> 6, lane = tid & 63;
  const int quad = lane >> 4, ln = lane & 15;
  const int rowBase = blockIdx.x * 128;

  // stage Wt[n][k] bf16 from W1 fp32 [64][128]
  #pragma unroll
  for (int it = 0; it < 8; ++it) {
    int idx = it * 256 + tid;
    int k = idx >> 5, n4 = idx & 31;
    float4 wv1 = *(const float4*)(W1 + k * 128 + n4 * 4);
    Ws[(n4 * 4 + 0) * APAD + k] = f2bf(wv1.x);
    Ws[(n4 * 4 + 1) * APAD + k] = f2bf(wv1.y);
    Ws[(n4 * 4 + 2) * APAD + k] = f2bf(wv1.z);
    Ws[(n4 * 4 + 3) * APAD + k] = f2bf(wv1.w);
  }
  // stage As tile from comb (coalesced bf16x8)
  #pragma unroll
  for (int it = 0; it < 4; ++it) {
    int idx = it * 256 + tid;           // 1024 uint4 = 128 rows x 8
    int row = idx >> 3, ch = idx & 7;
    int g = rowBase * 8 + idx;
    uint4 u = (g < N_NODES * 8) ? ((const uint4*)comb)[g] : make_uint4(0, 0, 0, 0);
    *(uint4*)&As[row * APAD + ch * 8] = u;
  }
  __syncthreads();

  f32x4 acc[2][8];
  #pragma unroll
  for (int mt = 0; mt < 2; ++mt) {
    #pragma unroll
    for (int nt = 0; nt < 8; ++nt) acc[mt][nt] = (f32x4)0.0f;
  }
  const int rw = wv * 32;
  #pragma unroll
  for (int kb = 0; kb < 2; ++kb) {
    short8 a0 = *(short8*)&As[(rw + ln) * APAD + kb * 32 + quad * 8];
    short8 a1 = *(short8*)&As[(rw + 16 + ln) * APAD + kb * 32 + quad * 8];
    #pragma unroll
    for (int nt = 0; nt < 8; ++nt) {
      short8 b = *(short8*)&Ws[(nt * 16 + ln) * APAD + kb * 32 + quad * 8];
      acc[0][nt] = __builtin_amdgcn_mfma_f32_16x16x32_bf16(a0, b, acc[0][nt], 0, 0, 0);
      acc[1][nt] = __builtin_amdgcn_mfma_f32_16x16x32_bf16(a1, b, acc[1][nt], 0, 0, 0);
    }
  }

  float bias[8], s[8], q[8];
  #pragma unroll
  for (int nt = 0; nt < 8; ++nt) { bias[nt] = b1[nt * 16 + ln]; s[nt] = 0.f; q[nt] = 0.f; }
  #pragma unroll
  for (int mt = 0; mt < 2; ++mt) {
    #pragma unroll
    for (int i = 0; i < 4; ++i) {
      int gRow = rowBase + rw + mt * 16 + quad * 4 + i;
      if (gRow < N_NODES) {
        #pragma unroll
        for (int nt = 0; nt < 8; ++nt) {
          float v = acc[mt][nt][i] + bias[nt];
          h1[gRow * 128 + nt * 16 + ln] = f2bf(v);
          s[nt] += v; q[nt] += v * v;
        }
      }
    }
  }
  #pragma unroll
  for (int nt = 0; nt < 8; ++nt) {
    s[nt] += __shfl_xor(s[nt], 16); s[nt] += __shfl_xor(s[nt], 32);
    q[nt] += __shfl_xor(q[nt], 16); q[nt] += __shfl_xor(q[nt], 32);
  }
  if (lane < 16) {
    #pragma unroll
    for (int nt = 0; nt < 8; ++nt) red[wv][nt * 16 + ln] = s[nt];
  }
  __syncthreads();
  if (tid < 128) DEV_ATOMIC_ADD(&stats[S1SUM + tid],
                                red[0][tid] + red[1][tid] + red[2][tid] + red[3][tid]);
  __syncthreads();
  if (lane < 16) {
    #pragma unroll
    for (int nt = 0; nt < 8; ++nt) red[wv][nt * 16 + ln] = q[nt];
  }
  __syncthreads();
  if (tid < 128) DEV_ATOMIC_ADD(&stats[S1SQ + tid],
                                red[0][tid] + red[1][tid] + red[2][tid] + red[3][tid]);
}

// ---- gemm2: h2(bf16) = relu(bn1(h1)) @ W2 + b2 (bf16 MFMA), fused BN2 raw stats ----
#define WPAD 136
__global__ __launch_bounds__(256) void k_gemm2(const unsigned short* __restrict__ h1,
                                               const float* __restrict__ W2,
                                               const float* __restrict__ b2,
                                               const float* __restrict__ g1,
                                               const float* __restrict__ be1,
                                               unsigned short* __restrict__ h2,
                                               float* __restrict__ stats) {
  __shared__ unsigned short As[128 * APAD];
  __shared__ unsigned short Ws[64 * WPAD];
  __shared__ float red[4][64];
  __shared__ float scL[128], shL[128];
  const int tid = threadIdx.x;
  const int wv = tid >> 6, lane = tid & 63;
  const int quad = lane >> 4, ln = lane & 15;
  const int rowBase = blockIdx.x * 128;

  if (tid < 128) {
    float mean = stats[S1SUM + tid] * (1.0f / N_NODES);
    float var = stats[S1SQ + tid] * (1.0f / N_NODES) - mean * mean;
    var = fmaxf(var, 0.0f);
    float sc = g1[tid] * rsqrtf(var + BN_EPS);
    scL[tid] = sc;
    shL[tid] = be1[tid] - mean * sc;
  }
  #pragma unroll
  for (int it = 0; it < 8; ++it) {
    int idx = it * 256 + tid;
    int k = idx >> 4, n4 = idx & 15;
    float4 wv2 = *(const float4*)(W2 + k * 64 + n4 * 4);
    Ws[(n4 * 4 + 0) * WPAD + k] = f2bf(wv2.x);
    Ws[(n4 * 4 + 1) * WPAD + k] = f2bf(wv2.y);
    Ws[(n4 * 4 + 2) * WPAD + k] = f2bf(wv2.z);
    Ws[(n4 * 4 + 3) * WPAD + k] = f2bf(wv2.w);
  }

  f32x4 acc[2][4];
  #pragma unroll
  for (int mt = 0; mt < 2; ++mt) {
    #pragma unroll
    for (int nt = 0; nt < 4; ++nt) acc[mt][nt] = (f32x4)0.0f;
  }
  const int rw = wv * 32;

  for (int kc = 0; kc < 2; ++kc) {
    __syncthreads();
    #pragma unroll
    for (int it = 0; it < 4; ++it) {
      int idx = it * 256 + tid;
      int row = idx >> 3, ch = idx & 7;
      int gRow = rowBase + row;
      uint4 u = (gRow < N_NODES) ? *(const uint4*)(h1 + gRow * 128 + kc * 64 + ch * 8)
                                 : make_uint4(0, 0, 0, 0);
      int kb = kc * 64 + ch * 8;
      float f0 = fmaxf(bflo(u.x) * scL[kb + 0] + shL[kb + 0], 0.f);
      float f1 = fmaxf(bfhi(u.x) * scL[kb + 1] + shL[kb + 1], 0.f);
      float f2 = fmaxf(bflo(u.y) * scL[kb + 2] + shL[kb + 2], 0.f);
      float f3 = fmaxf(bfhi(u.y) * scL[kb + 3] + shL[kb + 3], 0.f);
      float f4 = fmaxf(bflo(u.z) * scL[kb + 4] + shL[kb + 4], 0.f);
      float f5 = fmaxf(bfhi(u.z) * scL[kb + 5] + shL[kb + 5], 0.f);
      float f6 = fmaxf(bflo(u.w) * scL[kb + 6] + shL[kb + 6], 0.f);
      float f7 = fmaxf(bfhi(u.w) * scL[kb + 7] + shL[kb + 7], 0.f);
      uint4 o;
      o.x = (unsigned)f2bf(f0) | ((unsigned)f2bf(f1) << 16);
      o.y = (unsigned)f2bf(f2) | ((unsigned)f2bf(f3) << 16);
      o.z = (unsigned)f2bf(f4) | ((unsigned)f2bf(f5) << 16);
      o.w = (unsigned)f2bf(f6) | ((unsigned)f2bf(f7) << 16);
      *(uint4*)&As[row * APAD + ch * 8] = o;
    }
    __syncthreads();
    #pragma unroll
    for (int kb = 0; kb < 2; ++kb) {
      short8 a0 = *(short8*)&As[(rw + ln) * APAD + kb * 32 + quad * 8];
      short8 a1 = *(short8*)&As[(rw + 16 + ln) * APAD + kb * 32 + quad * 8];
      #pragma unroll
      for (int nt = 0; nt < 4; ++nt) {
        short8 b = *(short8*)&Ws[(nt * 16 + ln) * WPAD + kc * 64 + kb * 32 + quad * 8];
        acc[0][nt] = __builtin_amdgcn_mfma_f32_16x16x32_bf16(a0, b, acc[0][nt], 0, 0, 0);
        acc[1][nt] = __builtin_amdgcn_mfma_f32_16x16x32_bf16(a1, b, acc[1][nt], 0, 0, 0);
      }
    }
  }

  float bias[4], s[4], q[4];
  #pragma unroll
  for (int nt = 0; nt < 4; ++nt) { bias[nt] = b2[nt * 16 + ln]; s[nt] = 0.f; q[nt] = 0.f; }
  #pragma unroll
  for (int mt = 0; mt < 2; ++mt) {
    #pragma unroll
    for (int i = 0; i < 4; ++i) {
      int gRow = rowBase + rw + mt * 16 + quad * 4 + i;
      if (gRow < N_NODES) {
        #pragma unroll
        for (int nt = 0; nt < 4; ++nt) {
          float v = acc[mt][nt][i] + bias[nt];
          h2[gRow * 64 + nt * 16 + ln] = f2bf(v);
          s[nt] += v; q[nt] += v * v;
        }
      }
    }
  }
  #pragma unroll
  for (int nt = 0; nt < 4; ++nt) {
    s[nt] += __shfl_xor(s[nt], 16); s[nt] += __shfl_xor(s[nt], 32);
    q[nt] += __shfl_xor(q[nt], 16); q[nt] += __shfl_xor(q[nt], 32);
  }
  if (lane < 16) {
    #pragma unroll
    for (int nt = 0; nt < 4; ++nt) red[wv][nt * 16 + ln] = s[nt];
  }
  __syncthreads();
  if (tid < 64) DEV_ATOMIC_ADD(&stats[S2SUM + tid],
                               red[0][tid] + red[1][tid] + red[2][tid] + red[3][tid]);
  __syncthreads();
  if (lane < 16) {
    #pragma unroll
    for (int nt = 0; nt < 4; ++nt) red[wv][nt * 16 + ln] = q[nt];
  }
  __syncthreads();
  if (tid < 64) DEV_ATOMIC_ADD(&stats[S2SQ + tid],
                               red[0][tid] + red[1][tid] + red[2][tid] + red[3][tid]);
}

// ---- out = bn2(h2 bf16), per-block BN2 finalize ----
__global__ __launch_bounds__(256) void k_out(const unsigned short* __restrict__ h2,
                                             const float* __restrict__ stats,
                                             const float* __restrict__ g2,
                                             const float* __restrict__ be2,
                                             float* __restrict__ out) {
  __shared__ float scL[64], shL[64];
  const int tid = threadIdx.x;
  if (tid < 64) {
    float mean = stats[S2SUM + tid] * (1.0f / N_NODES);
    float var = stats[S2SQ + tid] * (1.0f / N_NODES) - mean * mean;
    var = fmaxf(var, 0.0f);
    float sc = g2[tid] * rsqrtf(var + BN_EPS);
    scL[tid] = sc;
    shL[tid] = be2[tid] - mean * sc;
  }
  __syncthreads();
  int i = blockIdx.x * 256 + tid;
  if (i < N_NODES * OUT_DIM / 4) {
    int c = i & 15;
    uint2 u = *(const uint2*)(h2 + i * 4);
    float4 v = {bflo(u.x), bfhi(u.x), bflo(u.y), bfhi(u.y)};
    float4 sc = ((const float4*)scL)[c];
    float4 sh = ((const float4*)shL)[c];
    v.x = v.x * sc.x + sh.x;
    v.y = v.y * sc.y + sh.y;
    v.z = v.z * sc.z + sh.z;
    v.w = v.w * sc.w + sh.w;
    ((float4*)out)[i] = v;
  }
}

extern "C" void kernel_launch(void* const* d_in, const int* in_sizes, int n_in,
                              void* d_out, int out_size, void* d_ws, size_t ws_size,
                              hipStream_t stream) {
  const float* x   = (const float*)d_in[0];
  const int*   ei  = (const int*)d_in[1];
  const float* eps = (const float*)d_in[2];
  const float* W1  = (const float*)d_in[3];
  const float* b1  = (const float*)d_in[4];
  const float* g1  = (const float*)d_in[5];
  const float* be1 = (const float*)d_in[6];
  const float* W2  = (const float*)d_in[7];
  const float* b2  = (const float*)d_in[8];
  const float* g2  = (const float*)d_in[9];
  const float* be2 = (const float*)d_in[10];

  float* ws = (float*)d_ws;
  unsigned short* xb     = (unsigned short*)(ws + OFF_XB);
  int*            binned = (int*)(ws + OFF_BINNED);
  unsigned short* comb   = (unsigned short*)(ws + OFF_COMB);
  unsigned short* h1     = (unsigned short*)(ws + OFF_H1);
  unsigned short* h2     = (unsigned short*)(ws + OFF_H2);
  float*          stats  = ws + OFF_STATS;
  int*            bcnt   = (int*)(stats + 768);   // NBINS=782 ints
  float*          out    = (float*)d_out;

  // memset covers stats(768) + bcnt(782)
  hipMemsetAsync(stats, 0, (768 + NBINS) * sizeof(float), stream);

  const int edgeGrid = (N_EDGES + 2047) / 2048;            // 782
  const int gemmGrid = (N_NODES + 127) / 128;              // 782
  k_bsplit<<<edgeGrid, 256, 0, stream>>>(x, xb, ei, bcnt, binned);
  k_bingather<<<NBINS, 512, 0, stream>>>(xb, eps, bcnt, binned, comb);
  k_gemm1<<<gemmGrid, 256, 0, stream>>>(comb, W1, b1, h1, stats);
  k_gemm2<<<gemmGrid, 256, 0, stream>>>(h1, W2, b2, g1, be1, h2, stats);
  k_out<<<(N_NODES * OUT_DIM / 4 + 255) / 256, 256, 0, stream>>>(h2, stats, g2, be2, out);
}